// Round 1
// baseline (259.301 us; speedup 1.0000x reference)
//
#include <hip/hip_runtime.h>
#include <hip/hip_bf16.h>
#include <stdint.h>

#define DEVINL __device__ __forceinline__

typedef __attribute__((ext_vector_type(8))) short bf16x8;     // 8 bf16 = 4 VGPRs (MFMA A/B frag)
typedef __attribute__((ext_vector_type(4))) short short4v;
typedef __attribute__((ext_vector_type(8))) unsigned short ushort8;
typedef __attribute__((ext_vector_type(4))) float f32x4;

DEVINL unsigned short f2bf(float x) {
  union { float f; uint32_t u; } v; v.f = x;
  uint32_t u = v.u;
  u += 0x7fffu + ((u >> 16) & 1u);   // RNE
  return (unsigned short)(u >> 16);
}

DEVINL void gload_lds16(const void* g, void* l) {
  __builtin_amdgcn_global_load_lds((const __attribute__((address_space(1))) void*)g,
                                   (__attribute__((address_space(3))) void*)l, 16, 0, 0);
}

// ---------------------------------------------------------------------------
// fp32 -> bf16 convert (vectorized, 8 elems/thread)
// ---------------------------------------------------------------------------
__global__ void cvt_f32_bf16(const float* __restrict__ in, unsigned short* __restrict__ out, int n) {
  int i = (blockIdx.x * blockDim.x + threadIdx.x) * 8;
  if (i >= n) return;
  float4 a = *(const float4*)(in + i);
  float4 b = *(const float4*)(in + i + 4);
  ushort8 r;
  r[0] = f2bf(a.x); r[1] = f2bf(a.y); r[2] = f2bf(a.z); r[3] = f2bf(a.w);
  r[4] = f2bf(b.x); r[5] = f2bf(b.y); r[6] = f2bf(b.z); r[7] = f2bf(b.w);
  *(ushort8*)(out + i) = r;
}

// ---------------------------------------------------------------------------
// W [K=1024][N=1024] fp32  ->  Wt [N][K] bf16   (tiled transpose via LDS)
// ---------------------------------------------------------------------------
__global__ __launch_bounds__(256) void transpose_w(const float* __restrict__ w,
                                                   unsigned short* __restrict__ wt) {
  __shared__ float tile[64][65];
  int k0 = blockIdx.y * 64, n0 = blockIdx.x * 64;
  int t = threadIdx.x;
  for (int i = 0; i < 4; ++i) {
    int r = (t >> 4) + i * 16;
    int c = (t & 15) * 4;
    float4 v = *(const float4*)(w + (size_t)(k0 + r) * 1024 + n0 + c);
    tile[r][c] = v.x; tile[r][c + 1] = v.y; tile[r][c + 2] = v.z; tile[r][c + 3] = v.w;
  }
  __syncthreads();
  for (int i = 0; i < 4; ++i) {
    int rn = (t >> 4) + i * 16;   // n offset
    int ck = (t & 15) * 4;        // k offset
    short4v o;
    o[0] = (short)f2bf(tile[ck + 0][rn]);
    o[1] = (short)f2bf(tile[ck + 1][rn]);
    o[2] = (short)f2bf(tile[ck + 2][rn]);
    o[3] = (short)f2bf(tile[ck + 3][rn]);
    *(short4v*)(wt + (size_t)(n0 + rn) * 1024 + k0 + ck) = o;
  }
}

// ---------------------------------------------------------------------------
// C = (A[4096][1024]bf16 @ Bt[1024][1024]bf16^T + bias) * scale
// mode 0: write bf16 head-split [H=16][B=2][S=2048][64]  (for Q/K/V proj)
// mode 1: write fp32 row-major [4096][1024]              (final out proj)
// 128x128 tile, BK=32, 4 waves (2x2), 4x4 16x16x32 frags per wave (m97 shape)
// ---------------------------------------------------------------------------
__global__ __launch_bounds__(256) void gemm_bt(
    const unsigned short* __restrict__ A,
    const unsigned short* __restrict__ Bt,
    const float* __restrict__ bias,
    void* __restrict__ out, float scale, int mode) {
  constexpr int K = 1024;
  __shared__ unsigned short Alds[128 * 32];
  __shared__ unsigned short Blds[128 * 32];
  int tile_m = blockIdx.x * 128;
  int tile_n = blockIdx.y * 128;
  int t = threadIdx.x, lane = t & 63, wid = t >> 6;
  int wm = wid >> 1, wn = wid & 1;
  int fr = lane & 15, fq = lane >> 4;
  f32x4 acc[4][4] = {};

  for (int k0 = 0; k0 < K; k0 += 32) {
    __syncthreads();   // previous iter's ds_reads done before restage
    for (int i = 0; i < 2; ++i) {
      int ebase = wid * 1024 + i * 512;       // element base in tile (1024B per wave-inst)
      int e = ebase + lane * 8;
      int r = e >> 5, c = e & 31;
      gload_lds16(A  + (size_t)(tile_m + r) * K + k0 + c, Alds + ebase);
      gload_lds16(Bt + (size_t)(tile_n + r) * K + k0 + c, Blds + ebase);
    }
    __syncthreads();   // vmcnt(0) drain: tiles resident
    bf16x8 af[4], bfb[4];
    for (int i = 0; i < 4; ++i)
      af[i] = *(const bf16x8*)(Alds + (wm * 64 + i * 16 + fr) * 32 + fq * 8);
    for (int j = 0; j < 4; ++j)
      bfb[j] = *(const bf16x8*)(Blds + (wn * 64 + j * 16 + fr) * 32 + fq * 8);
    for (int i = 0; i < 4; ++i)
      for (int j = 0; j < 4; ++j)
        acc[i][j] = __builtin_amdgcn_mfma_f32_16x16x32_bf16(af[i], bfb[j], acc[i][j], 0, 0, 0);
  }

  for (int i = 0; i < 4; ++i) {
    for (int j = 0; j < 4; ++j) {
      int n = tile_n + wn * 64 + j * 16 + fr;
      float bv = bias[n];
      for (int r = 0; r < 4; ++r) {
        int m = tile_m + wm * 64 + i * 16 + fq * 4 + r;
        float vv = (acc[i][j][r] + bv) * scale;
        if (mode == 0) {
          // head-split: hb = h*2 + b, h = n>>6, b = m>>11, s = m&2047, d = n&63
          size_t idx = (size_t)((n >> 6) * 2 + (m >> 11)) * (2048 * 64)
                     + (size_t)(m & 2047) * 64 + (n & 63);
          ((unsigned short*)out)[idx] = f2bf(vv);
        } else {
          ((float*)out)[(size_t)m * 1024 + n] = vv;
        }
      }
    }
  }
}

// ---------------------------------------------------------------------------
// Flash attention: Qh/Kh/Vh bf16 [32 hb][2048][64]; Q pre-scaled by 1/8.
// Block = 4 waves, 64 q-rows (16 per wave). K-tiles of 64 keys.
// K LDS XOR-swizzled (pre-swizzled global src for global_load_lds, m173).
// V staged transposed [d][k] (padded), P via padded LDS round-trip.
// Output: merged bf16 [B*S=4096][1024]
// ---------------------------------------------------------------------------
__global__ __launch_bounds__(256) void attn_fwd(
    const unsigned short* __restrict__ Qh,
    const unsigned short* __restrict__ Kh,
    const unsigned short* __restrict__ Vh,
    unsigned short* __restrict__ O) {
  constexpr int S = 2048, DK = 64;
  __shared__ unsigned short Klds[64 * 64];      // swizzled rows
  __shared__ unsigned short Vt[64 * 72];        // [d][k], padded stride 72
  __shared__ unsigned short Plds[4][16 * 72];   // per-wave P, padded stride 72

  int hb = blockIdx.y;
  int q0 = blockIdx.x * 64;
  int t = threadIdx.x, lane = t & 63, wid = t >> 6;
  int fr = lane & 15, fq = lane >> 4;

  const unsigned short* Qbase = Qh + (size_t)hb * S * DK;
  const unsigned short* Kbase = Kh + (size_t)hb * S * DK;
  const unsigned short* Vbase = Vh + (size_t)hb * S * DK;

  bf16x8 qf[2];
  for (int kk = 0; kk < 2; ++kk)
    qf[kk] = *(const bf16x8*)(Qbase + (size_t)(q0 + wid * 16 + fr) * DK + kk * 32 + fq * 8);

  float mrow[4], lrow[4];
  f32x4 oacc[4] = {};
  for (int r = 0; r < 4; ++r) { mrow[r] = -1e30f; lrow[r] = 0.f; }

  for (int kt = 0; kt < S / 64; ++kt) {
    __syncthreads();   // prior tile's LDS reads complete
    {
      // ---- stage K tile (8 KB, contiguous) swizzled via pre-swizzled source
      const unsigned short* Ksrc = Kbase + (size_t)kt * 64 * DK;
      for (int i = 0; i < 2; ++i) {
        int ebase = wid * 1024 + i * 512;
        int e = ebase + lane * 8;
        int r = e >> 6;                       // row (64 el/row)
        int cb = e & 63;                      // col element (mult of 8)
        int csw = cb ^ ((r & 7) << 3);        // element-level swizzle (16B chunks)
        gload_lds16(Ksrc + r * 64 + csw, Klds + ebase);
      }
      // ---- stage V transposed: thread t loads V[r][c0..c0+15], writes Vt[c][r]
      int r = t >> 2, c0 = (t & 3) * 16;
      const unsigned short* vsrc = Vbase + (size_t)(kt * 64 + r) * DK + c0;
      ushort8 v0 = *(const ushort8*)(vsrc);
      ushort8 v1 = *(const ushort8*)(vsrc + 8);
      for (int j = 0; j < 8; ++j) Vt[(c0 + j) * 72 + r] = v0[j];
      for (int j = 0; j < 8; ++j) Vt[(c0 + 8 + j) * 72 + r] = v1[j];
    }
    __syncthreads();   // K + Vt resident

    // ---- S = Q K^T  (scale already folded into Q)
    f32x4 sacc[4];
    for (int n0 = 0; n0 < 4; ++n0) {
      f32x4 z = {};
      for (int kk = 0; kk < 2; ++kk) {
        int row = n0 * 16 + fr;
        int cb = (kk * 32 + fq * 8) ^ ((row & 7) << 3);
        bf16x8 kf = *(const bf16x8*)(Klds + row * 64 + cb);
        z = __builtin_amdgcn_mfma_f32_16x16x32_bf16(qf[kk], kf, z, 0, 0, 0);
      }
      sacc[n0] = z;
    }

    // ---- online softmax (rows live in 16-lane groups; r -> q row fq*4+r)
    for (int r = 0; r < 4; ++r) {
      float mx = fmaxf(fmaxf(sacc[0][r], sacc[1][r]), fmaxf(sacc[2][r], sacc[3][r]));
      for (int msk = 1; msk <= 8; msk <<= 1) mx = fmaxf(mx, __shfl_xor(mx, msk, 64));
      float mnew = fmaxf(mrow[r], mx);
      float cf = __expf(mrow[r] - mnew);
      mrow[r] = mnew;
      float psum = 0.f;
      float p[4];
      for (int n0 = 0; n0 < 4; ++n0) {
        p[n0] = __expf(sacc[n0][r] - mnew);
        psum += p[n0];
      }
      for (int msk = 1; msk <= 8; msk <<= 1) psum += __shfl_xor(psum, msk, 64);
      lrow[r] = lrow[r] * cf + psum;
      for (int j = 0; j < 4; ++j) oacc[j][r] *= cf;
      for (int n0 = 0; n0 < 4; ++n0)
        Plds[wid][(fq * 4 + r) * 72 + n0 * 16 + fr] = f2bf(p[n0]);
    }
    __syncthreads();   // P visible (lgkmcnt drained)

    // ---- O += P @ V
    bf16x8 pf[2];
    for (int kk = 0; kk < 2; ++kk)
      pf[kk] = *(const bf16x8*)(&Plds[wid][fr * 72 + kk * 32 + fq * 8]);
    for (int j = 0; j < 4; ++j) {
      for (int kk = 0; kk < 2; ++kk) {
        bf16x8 vf = *(const bf16x8*)(Vt + (j * 16 + fr) * 72 + kk * 32 + fq * 8);
        oacc[j] = __builtin_amdgcn_mfma_f32_16x16x32_bf16(pf[kk], vf, oacc[j], 0, 0, 0);
      }
    }
  }

  // ---- epilogue: normalize, write merged layout [b*2048+q][h*64+d]
  int h = hb >> 1, b = hb & 1;
  for (int j = 0; j < 4; ++j) {
    for (int r = 0; r < 4; ++r) {
      int q = q0 + wid * 16 + fq * 4 + r;
      int d = j * 16 + fr;
      float vv = oacc[j][r] / lrow[r];
      O[(size_t)(b * 2048 + q) * 1024 + h * 64 + d] = f2bf(vv);
    }
  }
}

// ---------------------------------------------------------------------------
extern "C" void kernel_launch(void* const* d_in, const int* in_sizes, int n_in,
                              void* d_out, int out_size, void* d_ws, size_t ws_size,
                              hipStream_t stream) {
  const float* q   = (const float*)d_in[0];
  const float* k   = (const float*)d_in[1];
  const float* v   = (const float*)d_in[2];
  const float* w_q = (const float*)d_in[3];
  const float* b_q = (const float*)d_in[4];
  const float* w_k = (const float*)d_in[5];
  const float* b_k = (const float*)d_in[6];
  const float* w_v = (const float*)d_in[7];
  const float* b_v = (const float*)d_in[8];
  const float* w_o = (const float*)d_in[9];
  const float* b_o = (const float*)d_in[10];

  char* ws = (char*)d_ws;
  unsigned short* Xq  = (unsigned short*)(ws + 0);          // 8 MB  (reused as Obuf)
  unsigned short* Xk  = (unsigned short*)(ws + 8388608);
  unsigned short* Xv  = (unsigned short*)(ws + 16777216);
  unsigned short* Wtq = (unsigned short*)(ws + 25165824);   // 2 MB each
  unsigned short* Wtk = (unsigned short*)(ws + 27262976);
  unsigned short* Wtv = (unsigned short*)(ws + 29360128);
  unsigned short* Wto = (unsigned short*)(ws + 31457280);
  unsigned short* Qh  = (unsigned short*)(ws + 33554432);   // 8 MB each
  unsigned short* Kh  = (unsigned short*)(ws + 41943040);
  unsigned short* Vh  = (unsigned short*)(ws + 50331648);   // end = 58720256 (56 MB)
  unsigned short* Obuf = Xq;  // alias: Xq dead after Q projection

  const int NACT = 4096 * 1024;
  cvt_f32_bf16<<<NACT / 8 / 256, 256, 0, stream>>>(q, Xq, NACT);
  cvt_f32_bf16<<<NACT / 8 / 256, 256, 0, stream>>>(k, Xk, NACT);
  cvt_f32_bf16<<<NACT / 8 / 256, 256, 0, stream>>>(v, Xv, NACT);

  dim3 tg(16, 16);
  transpose_w<<<tg, 256, 0, stream>>>(w_q, Wtq);
  transpose_w<<<tg, 256, 0, stream>>>(w_k, Wtk);
  transpose_w<<<tg, 256, 0, stream>>>(w_v, Wtv);
  transpose_w<<<tg, 256, 0, stream>>>(w_o, Wto);

  dim3 gg(32, 8);  // M/128, N/128
  gemm_bt<<<gg, 256, 0, stream>>>(Xq, Wtq, b_q, Qh, 0.125f, 0);  // scale 1/sqrt(64)
  gemm_bt<<<gg, 256, 0, stream>>>(Xk, Wtk, b_k, Kh, 1.0f, 0);
  gemm_bt<<<gg, 256, 0, stream>>>(Xv, Wtv, b_v, Vh, 1.0f, 0);

  dim3 ag(32, 32);  // q-tiles, hb
  attn_fwd<<<ag, 256, 0, stream>>>(Qh, Kh, Vh, Obuf);

  gemm_bt<<<gg, 256, 0, stream>>>(Obuf, Wto, b_o, d_out, 1.0f, 1);
}

// Round 3
// 215.894 us; speedup vs baseline: 1.2011x; 1.2011x over previous
//
#include <hip/hip_runtime.h>
#include <hip/hip_bf16.h>
#include <stdint.h>

#define DEVINL __device__ __forceinline__

typedef __attribute__((ext_vector_type(8))) short bf16x8;     // 8 bf16 = 4 VGPRs (MFMA A/B frag)
typedef __attribute__((ext_vector_type(4))) short short4v;
typedef __attribute__((ext_vector_type(8))) unsigned short ushort8;
typedef __attribute__((ext_vector_type(4))) float f32x4;
typedef __attribute__((ext_vector_type(16))) float f32x16;

DEVINL unsigned short f2bf(float x) {
  union { float f; uint32_t u; } v; v.f = x;
  uint32_t u = v.u;
  u += 0x7fffu + ((u >> 16) & 1u);   // RNE
  return (unsigned short)(u >> 16);
}

DEVINL void gload_lds16(const void* g, void* l) {
  __builtin_amdgcn_global_load_lds((const __attribute__((address_space(1))) void*)g,
                                   (__attribute__((address_space(3))) void*)l, 16, 0, 0);
}

// ---------------------------------------------------------------------------
// fp32 -> bf16 convert (vectorized, 8 elems/thread)
// ---------------------------------------------------------------------------
__global__ void cvt_f32_bf16(const float* __restrict__ in, unsigned short* __restrict__ out, int n) {
  int i = (blockIdx.x * blockDim.x + threadIdx.x) * 8;
  if (i >= n) return;
  float4 a = *(const float4*)(in + i);
  float4 b = *(const float4*)(in + i + 4);
  ushort8 r;
  r[0] = f2bf(a.x); r[1] = f2bf(a.y); r[2] = f2bf(a.z); r[3] = f2bf(a.w);
  r[4] = f2bf(b.x); r[5] = f2bf(b.y); r[6] = f2bf(b.z); r[7] = f2bf(b.w);
  *(ushort8*)(out + i) = r;
}

// ---------------------------------------------------------------------------
// W [K=1024][N=1024] fp32  ->  Wt [N][K] bf16   (tiled transpose via LDS)
// ---------------------------------------------------------------------------
__global__ __launch_bounds__(256) void transpose_w(const float* __restrict__ w,
                                                   unsigned short* __restrict__ wt) {
  __shared__ float tile[64][65];
  int k0 = blockIdx.y * 64, n0 = blockIdx.x * 64;
  int t = threadIdx.x;
  for (int i = 0; i < 4; ++i) {
    int r = (t >> 4) + i * 16;
    int c = (t & 15) * 4;
    float4 v = *(const float4*)(w + (size_t)(k0 + r) * 1024 + n0 + c);
    tile[r][c] = v.x; tile[r][c + 1] = v.y; tile[r][c + 2] = v.z; tile[r][c + 3] = v.w;
  }
  __syncthreads();
  for (int i = 0; i < 4; ++i) {
    int rn = (t >> 4) + i * 16;   // n offset
    int ck = (t & 15) * 4;        // k offset
    short4v o;
    o[0] = (short)f2bf(tile[ck + 0][rn]);
    o[1] = (short)f2bf(tile[ck + 1][rn]);
    o[2] = (short)f2bf(tile[ck + 2][rn]);
    o[3] = (short)f2bf(tile[ck + 3][rn]);
    *(short4v*)(wt + (size_t)(n0 + rn) * 1024 + k0 + ck) = o;
  }
}

// ---------------------------------------------------------------------------
// Vh [hb][2048 s][64 d] bf16 -> Vt [hb][64 d][2048 s] bf16
// ---------------------------------------------------------------------------
__global__ __launch_bounds__(256) void transpose_act(const unsigned short* __restrict__ in,
                                                     unsigned short* __restrict__ out) {
  __shared__ unsigned short lds[64 * 72];
  int hb = blockIdx.y;
  int s0 = blockIdx.x * 64;
  int t = threadIdx.x;
  const unsigned short* src = in + (size_t)hb * 2048 * 64;
  unsigned short* dst = out + (size_t)hb * 64 * 2048;
  {
    int r = t >> 2, c0 = (t & 3) * 16;
    ushort8 v0 = *(const ushort8*)(src + (size_t)(s0 + r) * 64 + c0);
    ushort8 v1 = *(const ushort8*)(src + (size_t)(s0 + r) * 64 + c0 + 8);
    *(ushort8*)(&lds[r * 72 + c0]) = v0;
    *(ushort8*)(&lds[r * 72 + c0 + 8]) = v1;
  }
  __syncthreads();
  {
    int d = t >> 2, sc = (t & 3) * 16;
    ushort8 o0, o1;
    for (int j = 0; j < 8; ++j) o0[j] = lds[(sc + j) * 72 + d];
    for (int j = 0; j < 8; ++j) o1[j] = lds[(sc + 8 + j) * 72 + d];
    *(ushort8*)(dst + (size_t)d * 2048 + s0 + sc) = o0;
    *(ushort8*)(dst + (size_t)d * 2048 + s0 + sc + 8) = o1;
  }
}

// ---------------------------------------------------------------------------
// C = (A[4096][1024]bf16 @ Bt[1024][1024]bf16^T + bias) * scale
// mode 0: write bf16 head-split [H=16][B=2][S=2048][64]  (for Q/K/V proj)
// mode 1: write fp32 row-major [4096][1024]              (final out proj)
// ---------------------------------------------------------------------------
__global__ __launch_bounds__(256) void gemm_bt(
    const unsigned short* __restrict__ A,
    const unsigned short* __restrict__ Bt,
    const float* __restrict__ bias,
    void* __restrict__ out, float scale, int mode) {
  constexpr int K = 1024;
  __shared__ unsigned short Alds[128 * 32];
  __shared__ unsigned short Blds[128 * 32];
  int tile_m = blockIdx.x * 128;
  int tile_n = blockIdx.y * 128;
  int t = threadIdx.x, lane = t & 63, wid = t >> 6;
  int wm = wid >> 1, wn = wid & 1;
  int fr = lane & 15, fq = lane >> 4;
  f32x4 acc[4][4] = {};

  for (int k0 = 0; k0 < K; k0 += 32) {
    __syncthreads();
    for (int i = 0; i < 2; ++i) {
      int ebase = wid * 1024 + i * 512;
      int e = ebase + lane * 8;
      int r = e >> 5, c = e & 31;
      gload_lds16(A  + (size_t)(tile_m + r) * K + k0 + c, Alds + ebase);
      gload_lds16(Bt + (size_t)(tile_n + r) * K + k0 + c, Blds + ebase);
    }
    __syncthreads();
    bf16x8 af[4], bfb[4];
    for (int i = 0; i < 4; ++i)
      af[i] = *(const bf16x8*)(Alds + (wm * 64 + i * 16 + fr) * 32 + fq * 8);
    for (int j = 0; j < 4; ++j)
      bfb[j] = *(const bf16x8*)(Blds + (wn * 64 + j * 16 + fr) * 32 + fq * 8);
    for (int i = 0; i < 4; ++i)
      for (int j = 0; j < 4; ++j)
        acc[i][j] = __builtin_amdgcn_mfma_f32_16x16x32_bf16(af[i], bfb[j], acc[i][j], 0, 0, 0);
  }

  for (int i = 0; i < 4; ++i) {
    for (int j = 0; j < 4; ++j) {
      int n = tile_n + wn * 64 + j * 16 + fr;
      float bv = bias[n];
      for (int r = 0; r < 4; ++r) {
        int m = tile_m + wm * 64 + i * 16 + fq * 4 + r;
        float vv = (acc[i][j][r] + bv) * scale;
        if (mode == 0) {
          size_t idx = (size_t)((n >> 6) * 2 + (m >> 11)) * (2048 * 64)
                     + (size_t)(m & 2047) * 64 + (n & 63);
          ((unsigned short*)out)[idx] = f2bf(vv);
        } else {
          ((float*)out)[(size_t)m * 1024 + n] = vv;
        }
      }
    }
  }
}

// ---------------------------------------------------------------------------
// Flash attention (no inline asm this round — diagnostic bisect):
//  - 4 waves/block, 32 q-rows/wave (128 q/block); K-tiles of 64 keys
//  - 32x32x16 MFMA; swapped QK^T (mfma(K,Q)) -> scores col=lane&31=q
//  - in-register softmax; cross-half reduce via __shfl_xor(.,32)
//  - P -> bf16 via wave-private padded-LDS round-trip (write with C-layout
//    crow=(r&3)+8*(r>>2)+4*hi, read back in the V-operand convention)
//  - PV as O^T = mfma(Vt, P): O col=q -> lane-local rescale
//  - K and Vt staged linearly via global_load_lds, granule-XOR swizzle
//    (pre-swizzled global source); T1 bijective XCD swizzle
// Q pre-scaled by (1/8)*log2(e). Output merged bf16 [B*S=4096][1024].
// ---------------------------------------------------------------------------
__global__ __launch_bounds__(256) void attn_fwd(
    const unsigned short* __restrict__ Qh,
    const unsigned short* __restrict__ Kh,
    const unsigned short* __restrict__ Vtg,
    unsigned short* __restrict__ O) {
  constexpr int S = 2048, DK = 64;
  __shared__ unsigned short Klds[64 * 64];      // [key][d], granule-swizzled
  __shared__ unsigned short Vlds[64 * 64];      // [d][key], granule-swizzled
  __shared__ unsigned short Plds[4 * 32 * 72];  // per-wave P [q][key], stride 72

  int wg = blockIdx.x;
  int swz = (wg & 7) * 64 + (wg >> 3);          // bijective XCD swizzle (512 wgs)
  int hb = swz >> 4;          // 0..31
  int qt = swz & 15;          // 0..15
  int t = threadIdx.x, lane = t & 63, wid = t >> 6;
  int lq = lane & 31, hi = lane >> 5;
  int q0 = qt * 128;

  const unsigned short* Qb = Qh  + (size_t)hb * S * DK;
  const unsigned short* Kb = Kh  + (size_t)hb * S * DK;
  const unsigned short* Vb = Vtg + (size_t)hb * DK * S;

  // Q frags (B-operand): lane holds Q[q0+wid*32+lq][kk*16 + hi*8 .. +7]
  bf16x8 qf[4];
#pragma unroll
  for (int kk = 0; kk < 4; ++kk)
    qf[kk] = *(const bf16x8*)(Qb + (size_t)(q0 + wid * 32 + lq) * DK + kk * 16 + hi * 8);

  // staging addresses (LDS granule g holds source row=g>>3, chunk=(g&7)^(row&7))
  int g0 = wid * 128 + lane, g1 = g0 + 64;
  int sr0 = g0 >> 3, sc0 = ((g0 & 7) ^ (sr0 & 7)) * 8;
  int sr1 = g1 >> 3, sc1 = ((g1 & 7) ^ (sr1 & 7)) * 8;

  // fragment LDS element offsets
  int koff[2][4], voff[2][4];
#pragma unroll
  for (int h2 = 0; h2 < 2; ++h2) {
    int row = 32 * h2 + lq;
#pragma unroll
    for (int kk = 0; kk < 4; ++kk)
      koff[h2][kk] = (row * 8 + ((2 * kk + hi) ^ (row & 7))) * 8;
  }
#pragma unroll
  for (int jt = 0; jt < 2; ++jt) {
    int row = 32 * jt + lq;
#pragma unroll
    for (int ks = 0; ks < 4; ++ks)
      voff[jt][ks] = (row * 8 + ((2 * ks + hi) ^ (row & 7))) * 8;
  }

  unsigned short* Pw = Plds + wid * (32 * 72) + lq * 72;   // this lane's q-row

  float m = -INFINITY, l = 0.f;
  f32x16 oacc[2] = {};

  for (int kt = 0; kt < S / 64; ++kt) {
    __syncthreads();   // prior tile's LDS reads complete
    {
      const unsigned short* Ksrc = Kb + (size_t)kt * 64 * DK;
      const unsigned short* Vsrc = Vb + (size_t)kt * 64;
      gload_lds16(Ksrc + sr0 * 64 + sc0, Klds + g0 * 8);
      gload_lds16(Ksrc + sr1 * 64 + sc1, Klds + g1 * 8);
      gload_lds16(Vsrc + (size_t)sr0 * S + sc0, Vlds + g0 * 8);
      gload_lds16(Vsrc + (size_t)sr1 * S + sc1, Vlds + g1 * 8);
    }
    __syncthreads();   // tiles resident

    // ---- S^T = K Q^T : sacc[h2] reg r = S[key=32*h2+crow(r,hi)][q=lq]
    f32x16 sacc[2] = {};
#pragma unroll
    for (int kk = 0; kk < 4; ++kk) {
      bf16x8 k0 = *(const bf16x8*)(Klds + koff[0][kk]);
      sacc[0] = __builtin_amdgcn_mfma_f32_32x32x16_bf16(k0, qf[kk], sacc[0], 0, 0, 0);
      bf16x8 k1 = *(const bf16x8*)(Klds + koff[1][kk]);
      sacc[1] = __builtin_amdgcn_mfma_f32_32x32x16_bf16(k1, qf[kk], sacc[1], 0, 0, 0);
    }

    // ---- online softmax, in-register (log2 domain; log2e folded into Q)
    float pmax = sacc[0][0];
#pragma unroll
    for (int r = 1; r < 16; ++r) pmax = fmaxf(pmax, sacc[0][r]);
#pragma unroll
    for (int r = 0; r < 16; ++r) pmax = fmaxf(pmax, sacc[1][r]);
    pmax = fmaxf(pmax, __shfl_xor(pmax, 32, 64));   // cross-half: full 64-key max

    float mn = fmaxf(m, pmax);
    float cf = exp2f(m - mn);
    m = mn;
    l *= cf;
#pragma unroll
    for (int jt = 0; jt < 2; ++jt)
#pragma unroll
      for (int r = 0; r < 16; ++r) oacc[jt][r] *= cf;

    float psum = 0.f;
#pragma unroll
    for (int h2 = 0; h2 < 2; ++h2)
#pragma unroll
      for (int r = 0; r < 16; ++r) {
        float p = exp2f(sacc[h2][r] - m);
        sacc[h2][r] = p;
        psum += p;
      }
    psum += __shfl_xor(psum, 32, 64);               // full 64-key sum
    l += psum;

    // ---- P -> LDS (bf16, pairs of adjacent keys), then read PV A/B frags
#pragma unroll
    for (int h2 = 0; h2 < 2; ++h2)
#pragma unroll
      for (int rp = 0; rp < 8; ++rp) {
        uint32_t w = (uint32_t)f2bf(sacc[h2][2 * rp])
                   | ((uint32_t)f2bf(sacc[h2][2 * rp + 1]) << 16);
        int key = 32 * h2 + 8 * (rp >> 1) + 4 * hi + 2 * (rp & 1);  // crow of reg 2rp
        *(uint32_t*)(Pw + key) = w;
      }
    bf16x8 pfrag[4];
#pragma unroll
    for (int ks = 0; ks < 4; ++ks)
      pfrag[ks] = *(const bf16x8*)(Pw + 16 * ks + 8 * hi);

    // ---- O^T += V^T P^T : oacc[jt] reg r = O[q=lq][d=32*jt+crow(r,hi)]
#pragma unroll
    for (int jt = 0; jt < 2; ++jt)
#pragma unroll
      for (int ks = 0; ks < 4; ++ks) {
        bf16x8 vf = *(const bf16x8*)(Vlds + voff[jt][ks]);
        oacc[jt] = __builtin_amdgcn_mfma_f32_32x32x16_bf16(vf, pfrag[ks], oacc[jt], 0, 0, 0);
      }
  }

  // ---- epilogue: normalize (lane-local l), write merged [b*2048+q][h*64+d]
  int h = hb >> 1, b = hb & 1;
  int q = q0 + wid * 32 + lq;
  float linv = 1.0f / l;
  unsigned short* orow = O + (size_t)(b * 2048 + q) * 1024 + h * 64;
#pragma unroll
  for (int jt = 0; jt < 2; ++jt)
#pragma unroll
    for (int r = 0; r < 16; ++r) {
      int d = jt * 32 + (r & 3) + 8 * (r >> 2) + 4 * hi;
      orow[d] = f2bf(oacc[jt][r] * linv);
    }
}

// ---------------------------------------------------------------------------
extern "C" void kernel_launch(void* const* d_in, const int* in_sizes, int n_in,
                              void* d_out, int out_size, void* d_ws, size_t ws_size,
                              hipStream_t stream) {
  const float* q   = (const float*)d_in[0];
  const float* k   = (const float*)d_in[1];
  const float* v   = (const float*)d_in[2];
  const float* w_q = (const float*)d_in[3];
  const float* b_q = (const float*)d_in[4];
  const float* w_k = (const float*)d_in[5];
  const float* b_k = (const float*)d_in[6];
  const float* w_v = (const float*)d_in[7];
  const float* b_v = (const float*)d_in[8];
  const float* w_o = (const float*)d_in[9];
  const float* b_o = (const float*)d_in[10];

  char* ws = (char*)d_ws;
  unsigned short* Xq  = (unsigned short*)(ws + 0);          // 8 MB (reused as Obuf)
  unsigned short* Xk  = (unsigned short*)(ws + 8388608);    // 8 MB (reused as Vt)
  unsigned short* Xv  = (unsigned short*)(ws + 16777216);
  unsigned short* Wtq = (unsigned short*)(ws + 25165824);   // 2 MB each
  unsigned short* Wtk = (unsigned short*)(ws + 27262976);
  unsigned short* Wtv = (unsigned short*)(ws + 29360128);
  unsigned short* Wto = (unsigned short*)(ws + 31457280);
  unsigned short* Qh  = (unsigned short*)(ws + 33554432);   // 8 MB each
  unsigned short* Kh  = (unsigned short*)(ws + 41943040);
  unsigned short* Vh  = (unsigned short*)(ws + 50331648);   // end = 58720256 (56 MB)
  unsigned short* Obuf = Xq;   // Xq dead after Q projection
  unsigned short* Vt   = Xk;   // Xk dead after K projection

  const int NACT = 4096 * 1024;
  cvt_f32_bf16<<<NACT / 8 / 256, 256, 0, stream>>>(q, Xq, NACT);
  cvt_f32_bf16<<<NACT / 8 / 256, 256, 0, stream>>>(k, Xk, NACT);
  cvt_f32_bf16<<<NACT / 8 / 256, 256, 0, stream>>>(v, Xv, NACT);

  dim3 tg(16, 16);
  transpose_w<<<tg, 256, 0, stream>>>(w_q, Wtq);
  transpose_w<<<tg, 256, 0, stream>>>(w_k, Wtk);
  transpose_w<<<tg, 256, 0, stream>>>(w_v, Wtv);
  transpose_w<<<tg, 256, 0, stream>>>(w_o, Wto);

  dim3 gg(32, 8);  // M/128, N/128
  const float qscale = 0.125f * 1.44269504088896340736f;  // (1/sqrt 64) * log2(e)
  gemm_bt<<<gg, 256, 0, stream>>>(Xq, Wtq, b_q, Qh, qscale, 0);
  gemm_bt<<<gg, 256, 0, stream>>>(Xk, Wtk, b_k, Kh, 1.0f, 0);
  gemm_bt<<<gg, 256, 0, stream>>>(Xv, Wtv, b_v, Vh, 1.0f, 0);

  dim3 vtg(32, 32);  // s-tiles, hb
  transpose_act<<<vtg, 256, 0, stream>>>(Vh, Vt);

  attn_fwd<<<512, 256, 0, stream>>>(Qh, Kh, Vt, Obuf);

  gemm_bt<<<gg, 256, 0, stream>>>(Obuf, Wto, b_o, d_out, 1.0f, 1);
}